// Round 11
// baseline (43.218 us; speedup 1.0000x reference)
//
#include <hip/hip_runtime.h>
#include <math.h>

#define C_CH 256
#define KTOP 26
#define HWSZ 3136            // 56*56
#define NPIX 100352          // 32*3136
#define CHW  (C_CH * HWSZ)
#define PIX_PER_BLK 32
#define BLKS_PER_IMG 98      // 3136 / 32

typedef float f32x4 __attribute__((ext_vector_type(4)));

__device__ __forceinline__ void ce_desc(float& a, float& b) {
    float mx = fmaxf(a, b); float mn = fminf(a, b); a = mx; b = mn;
}
__device__ __forceinline__ void ce_asc(float& a, float& b) {
    float mn = fminf(a, b); float mx = fmaxf(a, b); a = mn; b = mx;
}

// Full bitonic sort of 32 values -> descending. 240 CE, static indices.
__device__ __forceinline__ void sort32_desc(float* v) {
#pragma unroll
    for (int k = 2; k <= 32; k <<= 1) {
#pragma unroll
        for (int j = k >> 1; j > 0; j >>= 1) {
#pragma unroll
            for (int i = 0; i < 32; ++i) {
                int l = i ^ j;
                if (l > i) {
                    if ((i & k) == 0) ce_desc(v[i], v[l]);
                    else              ce_asc(v[i], v[l]);
                }
            }
        }
    }
}

// Clean an already-bitonic 32 sequence -> descending. 80 CE.
__device__ __forceinline__ void clean32_desc(float* v) {
#pragma unroll
    for (int j = 16; j > 0; j >>= 1) {
#pragma unroll
        for (int i = 0; i < 32; ++i) {
            int l = i ^ j;
            if (l > i) ce_desc(v[i], v[l]);
        }
    }
}

// Merge own desc-26 (a[0..25]) with partner lane's desc-26 via shfl_xor.
// [a pad32 desc | rev(partner) pad32 asc] is bitonic-64; max-half keeps
// ranks 0..31 (bitonic), clean -> sorted desc. Both partners produce the
// identical multiset/sort. (LDS variant verified absmax=0, R2-R10)
__device__ __forceinline__ void shfl_merge26(float* a, int mask) {
    float h[32];
#pragma unroll
    for (int i = 0; i < 32; ++i) {
        float u = (i < KTOP)      ? a[i] : -INFINITY;
        float w = (31 - i < KTOP) ? __shfl_xor(a[31 - i], mask) : -INFINITY;
        h[i] = fmaxf(u, w);
    }
    clean32_desc(h);
#pragma unroll
    for (int j = 0; j < KTOP; ++j) a[j] = h[j];
}

__global__ __launch_bounds__(256, 4) void kwinners_kernel(
    const float* __restrict__ x, const float* __restrict__ duty,
    const float* __restrict__ bsp, float* __restrict__ out)
{
    __shared__ float s[264];                     // stride-33 per 32-ch group
    __shared__ float tile[C_CH][PIX_PER_BLK];    // 32 KB x-tile (quad-swizzled)
    __shared__ float thr_s[PIX_PER_BLK];
    // Total LDS ~= 33.9 KB -> 4 blocks/CU.

    const int t   = threadIdx.x;
    const int w   = t >> 6;                 // wave id (0..3)
    const int l   = t & 63;                 // lane
    const int g   = l >> 3;                 // channel group (0..7), 32 ch each
    const int p3  = l & 7;
    const int px  = w * 8 + p3;             // pixel within block (0..31)
    const int blk = blockIdx.x;
    const int b   = blk / BLKS_PER_IMG;
    const int hw0 = (blk - b * BLKS_PER_IMG) * PIX_PER_BLK;

    // ---- Stage tile with XOR-quad column swizzle: phys quad q of row r
    // holds logical quad q ^ (r>>5). Swizzle applied on the GLOBAL source
    // (LDS dest of global_load_lds must stay linear: base + lane*16).
    // Lane l -> row +(l>>3)=g, phys quad p3.
    {
#pragma unroll
        for (int it = 0; it < 8; ++it) {
            const int row = w * 64 + it * 8 + g;
            const int lq  = p3 ^ ((row >> 5) & 7);     // logical quad to fetch
            const float* gp = x + (size_t)b * CHW + (size_t)row * HWSZ
                                + hw0 + lq * 4;
            __builtin_amdgcn_global_load_lds(
                (const __attribute__((address_space(1))) void*)gp,
                (__attribute__((address_space(3))) void*)&tile[w * 64 + it * 8][0],
                16, 0, 0);
        }
    }

    // exp table while loads fly; stride-33 layout (bank-spread for boost read).
    // scale = exp(-bs*duty[c]); fp32 mul, exp in double rounded to fp32 ->
    // correctly-rounded. (absmax=0, R1-R10)
    {
        float bs = bsp[0];
        float m = -(bs * duty[t]);
        s[(t >> 5) * 33 + (t & 31)] = (float)exp((double)m);
    }
    __syncthreads();   // compiler drains vmcnt before s_barrier

    // ---- Boost own 32 channels from LDS (2 lanes/bank via swizzle), sort ----
    const int pcol = px ^ (g << 2);         // physical column for logical px
    float v[32];
#pragma unroll
    for (int i = 0; i < 32; ++i)
        v[i] = tile[g * 32 + i][pcol] * s[g * 33 + i];

    sort32_desc(v);                         // desc top-32 of own 32 channels

    // ---- L1: merge with lane^32 (group g^4): full 32-wide max-half ----
    float a[KTOP];
    {
        float h[32];
#pragma unroll
        for (int i = 0; i < 32; ++i)
            h[i] = fmaxf(v[i], __shfl_xor(v[31 - i], 32));
        clean32_desc(h);
#pragma unroll
        for (int j = 0; j < KTOP; ++j) a[j] = h[j];
    }
    // a = sorted top-26 of 64 channels {g, g^4}.

    // ---- L2: merge with lane^8 (group g^1) -> top-26 of 128 channels ----
    shfl_merge26(a, 8);

    // ---- L3: merge with lane^16 (group g^2) + rank-25 cascade ----
    float thr;
    {
        float h[32];
#pragma unroll
        for (int i = 0; i < 32; ++i) {
            float u  = (i < KTOP)      ? a[i] : -INFINITY;
            float pw = (31 - i < KTOP) ? __shfl_xor(a[31 - i], 16) : -INFINITY;
            h[i] = fmaxf(u, pw);                      // ranks 0..31 of 256, r=25
        }
        float l16[16];
#pragma unroll
        for (int i = 0; i < 16; ++i) l16[i] = fminf(h[i], h[i + 16]);    // r=9
        float l8[8];
#pragma unroll
        for (int i = 0; i < 8; ++i)  l8[i]  = fminf(l16[i], l16[i + 8]); // r=1
        float h4[4];
#pragma unroll
        for (int i = 0; i < 4; ++i)  h4[i]  = fmaxf(l8[i], l8[i + 4]);   // r=1
        float h2[2];
#pragma unroll
        for (int i = 0; i < 2; ++i)  h2[i]  = fmaxf(h4[i], h4[i + 2]);   // r=1
        thr = fminf(h2[0], h2[1]);
    }
    if (g == 0) thr_s[px] = thr;            // one lane per pixel publishes
    __syncthreads();

    // ---- Vectorized write: lane -> (r8 = l>>3, phys quad pg = l&7).
    // Physical quad pg of row r holds logical quad lq = pg ^ (r>>5).
    {
        const int pg = p3;
        const int r8 = g;
#pragma unroll
        for (int it = 0; it < 8; ++it) {
            const int r  = w * 64 + it * 8 + r8;
            const int lq = pg ^ ((r >> 5) & 7);
            const f32x4 xv = *reinterpret_cast<const f32x4*>(&tile[r][pg * 4]);
            const float scv = s[(r >> 5) * 33 + (r & 31)];
            const float t0 = thr_s[lq * 4 + 0];
            const float t1 = thr_s[lq * 4 + 1];
            const float t2 = thr_s[lq * 4 + 2];
            const float t3 = thr_s[lq * 4 + 3];
            f32x4 res;
            res.x = (xv.x * scv >= t0) ? xv.x : 0.0f;
            res.y = (xv.y * scv >= t1) ? xv.y : 0.0f;
            res.z = (xv.z * scv >= t2) ? xv.z : 0.0f;
            res.w = (xv.w * scv >= t3) ? xv.w : 0.0f;
            __builtin_nontemporal_store(
                res, reinterpret_cast<f32x4*>(
                    out + (size_t)b * CHW + (size_t)r * HWSZ + hw0 + lq * 4));
        }
    }
}

extern "C" void kernel_launch(void* const* d_in, const int* in_sizes, int n_in,
                              void* d_out, int out_size, void* d_ws, size_t ws_size,
                              hipStream_t stream) {
    const float* x    = (const float*)d_in[0];
    const float* duty = (const float*)d_in[1];
    // d_in[2] = k (int, ==26 hardcoded), d_in[3] = boost_strength (float)
    const float* bs   = (const float*)d_in[3];
    float* out = (float*)d_out;

    hipLaunchKernelGGL(kwinners_kernel, dim3(NPIX / PIX_PER_BLK), dim3(256), 0,
                       stream, x, duty, bs, out);
}

// Round 12
// 37.956 us; speedup vs baseline: 1.1386x; 1.1386x over previous
//
#include <hip/hip_runtime.h>
#include <math.h>

#define C_CH 256
#define KTOP 26
#define HWSZ 3136            // 56*56
#define NPIX 100352          // 32*3136
#define CHW  (C_CH * HWSZ)
#define PIX_PER_BLK 32
#define BLKS_PER_IMG 98      // 3136 / 32
#define CPT 32               // channels per lane-half (C_CH / 8)

typedef float f32x4 __attribute__((ext_vector_type(4)));

__device__ __forceinline__ void ce_desc(float& a, float& b) {
    float mx = fmaxf(a, b); float mn = fminf(a, b); a = mx; b = mn;
}
__device__ __forceinline__ void ce_asc(float& a, float& b) {
    float mn = fminf(a, b); float mx = fmaxf(a, b); a = mn; b = mx;
}

// Full bitonic sort of 32 values -> descending. 240 CE, static indices.
__device__ __forceinline__ void sort32_desc(float* v) {
#pragma unroll
    for (int k = 2; k <= 32; k <<= 1) {
#pragma unroll
        for (int j = k >> 1; j > 0; j >>= 1) {
#pragma unroll
            for (int i = 0; i < 32; ++i) {
                int l = i ^ j;
                if (l > i) {
                    if ((i & k) == 0) ce_desc(v[i], v[l]);
                    else              ce_asc(v[i], v[l]);
                }
            }
        }
    }
}

// Clean an already-bitonic 32 sequence -> descending. 80 CE.
__device__ __forceinline__ void clean32_desc(float* v) {
#pragma unroll
    for (int j = 16; j > 0; j >>= 1) {
#pragma unroll
        for (int i = 0; i < 32; ++i) {
            int l = i ^ j;
            if (l > i) ce_desc(v[i], v[l]);
        }
    }
}

// Merge own desc-26 (a[0..25]) with LDS desc-26 list -> a = sorted top-26 of
// union. [a pad32 desc | rev(src) pad32 asc] is bitonic-64; max-half keeps
// ranks 0..31 (bitonic), clean -> sorted desc. (verified R2-R10)
__device__ __forceinline__ void merge26(float* a, const float* __restrict__ src) {
    float h[32];
#pragma unroll
    for (int i = 0; i < 32; ++i) {
        float u = (i < KTOP)      ? a[i]        : -INFINITY;
        float w = (31 - i < KTOP) ? src[31 - i] : -INFINITY;
        h[i] = fmaxf(u, w);
    }
    clean32_desc(h);
#pragma unroll
    for (int j = 0; j < KTOP; ++j) a[j] = h[j];
}

__global__ __launch_bounds__(256, 4) void kwinners_kernel(
    const float* __restrict__ x, const float* __restrict__ duty,
    const float* __restrict__ bsp, float* __restrict__ out)
{
    __shared__ float s[C_CH];
    __shared__ float tile[C_CH][PIX_PER_BLK];    // 32 KB x-tile
    __shared__ float pub[2][PIX_PER_BLK][26];    // stride 26: 2-way (free)
    // threshold aliased into pub[0][pl][0] after pub[0] is dead (level-3).
    // Total LDS = 32768 + 1024 + 6656 = 40448 -> 4 blocks/CU.

    const int t   = threadIdx.x;
    const int w   = t >> 6;                 // wave id (0..3)
    const int l   = t & 63;                 // lane
    const int pl  = l & 31;                 // pixel within block
    const int hf  = l >> 5;                 // lane half
    const int blk = blockIdx.x;
    const int b   = blk / BLKS_PER_IMG;
    const int hw0 = (blk - b * BLKS_PER_IMG) * PIX_PER_BLK;

    // ---- Stage this wave's 64 channel-rows into LDS (async, no VGPR dest).
    // Per instr: 64 lanes x 16B = 8 rows of 32px; dest = uniform base + lane*16
    // (HW rule). Lane l -> row (l>>3), pixels (l&7)*4 .. +3.
    {
        const int row0 = w * 64;
        const float* gp = x + (size_t)b * CHW + (size_t)(row0 + (l >> 3)) * HWSZ
                            + hw0 + (l & 7) * 4;
#pragma unroll
        for (int it = 0; it < 8; ++it) {
            __builtin_amdgcn_global_load_lds(
                (const __attribute__((address_space(1))) void*)(gp + (size_t)it * 8 * HWSZ),
                (__attribute__((address_space(3))) void*)&tile[row0 + it * 8][0],
                16, 0, 0);
        }
    }

    // exp table while loads fly. Thread t (in wave w) writes s[t]; all later
    // reads of s / tile before the pub exchange are WAVE-LOCAL (wave w reads
    // only s[64w..64w+64) and tile rows [64w,64w+64)) -> no block barrier
    // needed here. scale = exp(-bs*duty[c]); fp32 mul, exp in double rounded
    // to fp32 -> correctly-rounded. (absmax=0, R1-R10)
    {
        float bs = bsp[0];
        float m = -(bs * duty[t]);
        s[t] = (float)exp((double)m);
    }

    // Wave-local drain of this wave's global_load_lds (replaces block-wide
    // __syncthreads): each wave proceeds as soon as ITS loads land.
    asm volatile("s_waitcnt vmcnt(0)" ::: "memory");
    __builtin_amdgcn_sched_barrier(0);

    const int c0 = w * 64 + hf * 32;        // this lane-half's channel group
    const float* sc = s + c0;

    // ---- Boost own 32 channels from LDS, sort desc ----
    float v[CPT];
#pragma unroll
    for (int i = 0; i < CPT; ++i) v[i] = tile[c0 + i][pl] * sc[i];

    sort32_desc(v);

    // ---- Level 1 (intra-wave): merge with partner half via shfl ----
    float a[KTOP];
    {
        float h[32];
#pragma unroll
        for (int i = 0; i < 32; ++i) {
            float u  = (i < KTOP)      ? v[i] : -INFINITY;
            float pw = (31 - i < KTOP) ? __shfl_xor(v[31 - i], 32) : -INFINITY;
            h[i] = fmaxf(u, pw);
        }
        clean32_desc(h);
#pragma unroll
        for (int j = 0; j < KTOP; ++j) a[j] = h[j];
    }
    // a = sorted top-26 of channels [64w, 64w+64), identical in both halves.

    // ---- Publish: wave1 -> pub[0], wave3 -> pub[1] ----
    if ((w & 1) && l < 32) {
        float* dst = pub[w >> 1][pl];
#pragma unroll
        for (int j = 0; j < KTOP; ++j) dst[j] = a[j];
    }
    __syncthreads();

    // ---- Level 2: wave0 <- pub[0], wave2 <- pub[1]; wave2 republishes ----
    if (w == 0) {
        merge26(a, pub[0][pl]);             // top-26 of ch 0..127
    } else if (w == 2) {
        merge26(a, pub[1][pl]);             // top-26 of ch 128..255
        if (l < 32) {
            float* dst = pub[1][pl];        // own source, safe to overwrite
#pragma unroll
            for (int j = 0; j < KTOP; ++j) dst[j] = a[j];
        }
    }
    __syncthreads();

    // ---- Level 3 (wave 0): rank-25 of merge(a, pub[1]) via cascade ----
    if (w == 0) {
        const float* src = pub[1][pl];
        float h[32];
#pragma unroll
        for (int i = 0; i < 32; ++i) {
            float u  = (i < KTOP)      ? a[i]        : -INFINITY;
            float wv = (31 - i < KTOP) ? src[31 - i] : -INFINITY;
            h[i] = fmaxf(u, wv);                      // ranks 0..31, r=25
        }
        float l16[16];
#pragma unroll
        for (int i = 0; i < 16; ++i) l16[i] = fminf(h[i], h[i + 16]);    // r=9
        float l8[8];
#pragma unroll
        for (int i = 0; i < 8; ++i)  l8[i]  = fminf(l16[i], l16[i + 8]); // r=1
        float h4[4];
#pragma unroll
        for (int i = 0; i < 4; ++i)  h4[i]  = fmaxf(l8[i], l8[i + 4]);   // r=1
        float h2[2];
#pragma unroll
        for (int i = 0; i < 2; ++i)  h2[i]  = fmaxf(h4[i], h4[i + 2]);   // r=1
        if (l < 32) pub[0][pl][0] = fminf(h2[0], h2[1]);   // thr (pub[0] dead)
    }
    __syncthreads();

    // ---- Vectorized write: lane -> (row8 = l>>3, px-group = l&7).
    // Per iter: ds_read_b128 (4 px of one row) + broadcast s[row] + 4 selects
    // + one NT dwordx4 store. 8 iters cover this wave's 64 rows x 32 px.
    {
        const int pg   = l & 7;             // pixel group (4 px)
        const int r8   = l >> 3;            // row within each 8-row step
        const int row0 = w * 64;
        const float t0 = pub[0][pg * 4 + 0][0];
        const float t1 = pub[0][pg * 4 + 1][0];
        const float t2 = pub[0][pg * 4 + 2][0];
        const float t3 = pub[0][pg * 4 + 3][0];

        float* opb = out + (size_t)b * CHW + (size_t)(row0 + r8) * HWSZ
                         + hw0 + pg * 4;
#pragma unroll
        for (int it = 0; it < 8; ++it) {
            const int r = row0 + it * 8 + r8;
            const f32x4 xv = *reinterpret_cast<const f32x4*>(&tile[r][pg * 4]);
            const float scv = s[r];
            f32x4 res;
            res.x = (xv.x * scv >= t0) ? xv.x : 0.0f;
            res.y = (xv.y * scv >= t1) ? xv.y : 0.0f;
            res.z = (xv.z * scv >= t2) ? xv.z : 0.0f;
            res.w = (xv.w * scv >= t3) ? xv.w : 0.0f;
            __builtin_nontemporal_store(
                res, reinterpret_cast<f32x4*>(&opb[(size_t)(it * 8) * HWSZ]));
        }
    }
}

extern "C" void kernel_launch(void* const* d_in, const int* in_sizes, int n_in,
                              void* d_out, int out_size, void* d_ws, size_t ws_size,
                              hipStream_t stream) {
    const float* x    = (const float*)d_in[0];
    const float* duty = (const float*)d_in[1];
    // d_in[2] = k (int, ==26 hardcoded), d_in[3] = boost_strength (float)
    const float* bs   = (const float*)d_in[3];
    float* out = (float*)d_out;

    hipLaunchKernelGGL(kwinners_kernel, dim3(NPIX / PIX_PER_BLK), dim3(256), 0,
                       stream, x, duty, bs, out);
}